// Round 1
// 523.220 us; speedup vs baseline: 1.1383x; 1.1383x over previous
//
#include <hip/hip_runtime.h>
#include <hip/hip_bf16.h>

// GhostLinear: out[m,o] = sum_k x[m,k] * lut[gidx[o,k]] * scale[o]
// M = B*S = 8192, N = OUT_F = 4096, K = IN_F = 4096.
// R4: GEMM rewritten as the 256x256 / BK=64 / 8-wave "8-phase" schedule
//     (counted vmcnt, raw s_barrier, setprio, conflict-free chunk^row XOR
//     swizzle via pre-swizzled global_load_lds sources). Dequant LUT staging
//     vectorized to float4. cvt_x unchanged.

typedef __bf16 bf16x8 __attribute__((ext_vector_type(8)));
typedef float f32x16 __attribute__((ext_vector_type(16)));

#define AS1(p) ((__attribute__((address_space(1))) void*)(p))
#define AS3(p) ((__attribute__((address_space(3))) void*)(p))

static constexpr int M_DIM = 8192;   // B*S
static constexpr int N_DIM = 4096;   // OUT_F
static constexpr int K_DIM = 4096;   // IN_F

// ---------------------------------------------------------------------------
// Kernel 1: dequant W -> bf16 via LDS-resident LUT. 512 blocks x 1024 thr.
// Two bf16 half-passes (64 KB LDS each), idx held in registers across passes.
// R4: staging loads vectorized (float4 -> 4x bf16 -> 8B LDS store).
// ---------------------------------------------------------------------------
__global__ __launch_bounds__(1024) void dequant_w_kernel(
    const int* __restrict__ idx, const float* __restrict__ lut,
    int4* __restrict__ wout) {
  __shared__ unsigned short lut_s[32768];   // 64 KB
  const int tid = threadIdx.x;
  const int4* i4 = (const int4*)idx;
  const float4* lut4 = (const float4*)lut;

  int4 ia[4], ib[4];
  union { unsigned short u[8]; int4 q; } o[4];
#pragma unroll
  for (int it = 0; it < 4; ++it) {
    const int w = blockIdx.x * 4096 + it * 1024 + tid;
    ia[it] = i4[2 * w];
    ib[it] = i4[2 * w + 1];
  }

  // pass 0: lut[0:32768)
#pragma unroll
  for (int i8 = 0; i8 < 8; ++i8) {
    const int c = i8 * 1024 + tid;          // [0, 8192)
    const float4 f = lut4[c];
    union { unsigned short u[4]; unsigned long long q; } s;
    __bf16 b0 = (__bf16)f.x, b1 = (__bf16)f.y, b2 = (__bf16)f.z, b3 = (__bf16)f.w;
    s.u[0] = *(const unsigned short*)&b0;
    s.u[1] = *(const unsigned short*)&b1;
    s.u[2] = *(const unsigned short*)&b2;
    s.u[3] = *(const unsigned short*)&b3;
    *(unsigned long long*)&lut_s[4 * c] = s.q;
  }
  __syncthreads();
#pragma unroll
  for (int it = 0; it < 4; ++it) {
    if (ia[it].x < 32768) o[it].u[0] = lut_s[ia[it].x];
    if (ia[it].y < 32768) o[it].u[1] = lut_s[ia[it].y];
    if (ia[it].z < 32768) o[it].u[2] = lut_s[ia[it].z];
    if (ia[it].w < 32768) o[it].u[3] = lut_s[ia[it].w];
    if (ib[it].x < 32768) o[it].u[4] = lut_s[ib[it].x];
    if (ib[it].y < 32768) o[it].u[5] = lut_s[ib[it].y];
    if (ib[it].z < 32768) o[it].u[6] = lut_s[ib[it].z];
    if (ib[it].w < 32768) o[it].u[7] = lut_s[ib[it].w];
  }
  __syncthreads();

  // pass 1: lut[32768:65536)
#pragma unroll
  for (int i8 = 0; i8 < 8; ++i8) {
    const int c = i8 * 1024 + tid;
    const float4 f = lut4[8192 + c];
    union { unsigned short u[4]; unsigned long long q; } s;
    __bf16 b0 = (__bf16)f.x, b1 = (__bf16)f.y, b2 = (__bf16)f.z, b3 = (__bf16)f.w;
    s.u[0] = *(const unsigned short*)&b0;
    s.u[1] = *(const unsigned short*)&b1;
    s.u[2] = *(const unsigned short*)&b2;
    s.u[3] = *(const unsigned short*)&b3;
    *(unsigned long long*)&lut_s[4 * c] = s.q;
  }
  __syncthreads();
#pragma unroll
  for (int it = 0; it < 4; ++it) {
    if (ia[it].x >= 32768) o[it].u[0] = lut_s[ia[it].x - 32768];
    if (ia[it].y >= 32768) o[it].u[1] = lut_s[ia[it].y - 32768];
    if (ia[it].z >= 32768) o[it].u[2] = lut_s[ia[it].z - 32768];
    if (ia[it].w >= 32768) o[it].u[3] = lut_s[ia[it].w - 32768];
    if (ib[it].x >= 32768) o[it].u[4] = lut_s[ib[it].x - 32768];
    if (ib[it].y >= 32768) o[it].u[5] = lut_s[ib[it].y - 32768];
    if (ib[it].z >= 32768) o[it].u[6] = lut_s[ib[it].z - 32768];
    if (ib[it].w >= 32768) o[it].u[7] = lut_s[ib[it].w - 32768];
    const int w = blockIdx.x * 4096 + it * 1024 + tid;
    wout[w] = o[it].q;
  }
}

// ---------------------------------------------------------------------------
// Kernel 2: x fp32 -> bf16. One thread -> 8 elements.
// ---------------------------------------------------------------------------
__global__ __launch_bounds__(256) void cvt_x_kernel(
    const float4* __restrict__ x, int4* __restrict__ aout) {
  const int t = blockIdx.x * 256 + threadIdx.x;     // 4,194,304 threads
  const float4 a = x[2 * t];
  const float4 b = x[2 * t + 1];
  union { bf16x8 v; int4 q; } u;
  u.v[0] = (__bf16)a.x;  u.v[1] = (__bf16)a.y;
  u.v[2] = (__bf16)a.z;  u.v[3] = (__bf16)a.w;
  u.v[4] = (__bf16)b.x;  u.v[5] = (__bf16)b.y;
  u.v[6] = (__bf16)b.z;  u.v[7] = (__bf16)b.w;
  aout[t] = u.q;
}

// ---------------------------------------------------------------------------
// Kernel 3: C[M,N] = A[M,K](bf16) * W[N,K](bf16)^T, fp32 out, scale fused.
// 256x256 block tile, BK=64, 512 threads = 8 waves (2 wr x 4 wc), wave tile
// 128x64 as a 4x2 grid of 32x32x16 bf16 MFMAs (4 K=16 substeps per tile).
//
// LDS (128 KiB dynamic):
//   A: [pi][hb][128 r'][8 chunks][16B]  at      pi*32768 + hb*16384
//   B: same at +65536.
//   A half hb holds rows r with ((r>>6)&1)==hb  (r' = (r&63) + 64*(r>>7));
//   B half hb holds rows n with ((n>>5)&1)==hb  (r' = (n&31) + 32*(n>>6)).
//   Chunk swizzle: LDS[hb][r'][p] holds global k-chunk  p ^ (r'&7)  -> every
//   wave64 ds_read_b128 (32 rows x 2 k-chunks) hits each bank exactly 8x
//   (conflict-free). Swizzle is applied on the *global source* address of
//   global_load_lds (LDS dest stays linear) and on the ds_read address.
//
// Per K-tile: 4 phases; each = {ds_read subtile | stage 1 half-tile (2x
// global_load_lds dwordx4) | s_barrier | lgkmcnt(0)+sched_barrier |
// setprio(1) 8x MFMA setprio(0) | counted vmcnt | s_barrier}. Staging order
// A0,B0,B1,A1 at P0..P3 one tile ahead; vmcnt(4) at P0/P1/P3 drains exactly
// the half-tile the next phase's ds_reads need (never 0 in the main loop).
// Fragment layouts (verified 32x32x16 family): A/B lane: m|n = lane&31,
// k = (lane>>5)*8 + e (per K=16 substep). C/D: col = lane&31,
// row = (reg&3) + 8*(reg>>2) + 4*(lane>>5).
// ---------------------------------------------------------------------------

__device__ __forceinline__ void load_af(bf16x8 af[2][4], const char* p,
                                        const int ck[4]) {
#pragma unroll
  for (int il = 0; il < 2; ++il)
#pragma unroll
    for (int t = 0; t < 4; ++t)
      af[il][t] = *(const bf16x8*)(p + il * 4096 + ck[t]);
}

__device__ __forceinline__ void load_bf(bf16x8 bf[4], const char* p,
                                        const int ck[4]) {
#pragma unroll
  for (int t = 0; t < 4; ++t)
    bf[t] = *(const bf16x8*)(p + ck[t]);
}

template <int HB, int J>
__device__ __forceinline__ void mma_quad(f32x16 acc[4][2],
                                         const bf16x8 af[2][4],
                                         const bf16x8 bf[4]) {
#pragma unroll
  for (int t = 0; t < 4; ++t)
#pragma unroll
    for (int il = 0; il < 2; ++il)
      acc[HB * 2 + il][J] = __builtin_amdgcn_mfma_f32_32x32x16_bf16(
          af[il][t], bf[t], acc[HB * 2 + il][J], 0, 0, 0);
}

#define BAR __builtin_amdgcn_s_barrier()
#define VMCNT4 asm volatile("s_waitcnt vmcnt(4)" ::: "memory")
#define LGKM0                                          \
  do {                                                 \
    asm volatile("s_waitcnt lgkmcnt(0)" ::: "memory"); \
    __builtin_amdgcn_sched_barrier(0);                 \
  } while (0)

#define ldsA(PI, HB) (lds + (PI) * 32768 + (HB) * 16384 + aBase)
#define ldsB(PI, JH) (lds + 65536 + (PI) * 32768 + (JH) * 16384 + bBase)

// A stage: rowA = (tid>>3) + q*128 + hb*64 ; chunk cc = (tid&7)^((tid>>3)&7)
#define STAGE_A(PI, HB, KN)                                                    \
  do {                                                                         \
    const size_t gofs = gA0 + (size_t)(HB)*524288 + (size_t)(KN)*2;            \
    __builtin_amdgcn_global_load_lds(                                          \
        AS1(Ag + gofs),                                                        \
        AS3(lds + (PI)*32768 + (HB)*16384 + tid * 16), 16, 0, 0);              \
    __builtin_amdgcn_global_load_lds(                                          \
        AS1(Ag + gofs + 1048576),                                              \
        AS3(lds + (PI)*32768 + (HB)*16384 + 8192 + tid * 16), 16, 0, 0);       \
  } while (0)

// B stage: n = (u&31) + 32*hb + 64*(u>>5) + 128*q  (u = tid>>3)
#define STAGE_B(PI, HB, KN)                                                    \
  do {                                                                         \
    const size_t gofs = gB0 + (size_t)(HB)*262144 + (size_t)(KN)*2;            \
    __builtin_amdgcn_global_load_lds(                                          \
        AS1(Bg + gofs),                                                        \
        AS3(lds + 65536 + (PI)*32768 + (HB)*16384 + tid * 16), 16, 0, 0);      \
    __builtin_amdgcn_global_load_lds(                                          \
        AS1(Bg + gofs + 1048576),                                              \
        AS3(lds + 65536 + (PI)*32768 + (HB)*16384 + 8192 + tid * 16), 16, 0,   \
        0);                                                                    \
  } while (0)

// One K-tile = 4 phases. Quadrants: (A-lo,B0) (A-lo,B1) (A-hi,B1) (A-hi,B0).
#define TILE(PI, KN)                        \
  do {                                      \
    /* P0 */                                \
    load_af(af, ldsA(PI, 0), ck);           \
    load_bf(bf, ldsB(PI, 0), ck);           \
    STAGE_A((PI) ^ 1, 0, KN);               \
    BAR;                                    \
    LGKM0;                                  \
    __builtin_amdgcn_s_setprio(1);          \
    mma_quad<0, 0>(acc, af, bf);            \
    __builtin_amdgcn_s_setprio(0);          \
    VMCNT4;                                 \
    BAR;                                    \
    /* P1 */                                \
    load_bf(bf, ldsB(PI, 1), ck);           \
    STAGE_B((PI) ^ 1, 0, KN);               \
    BAR;                                    \
    LGKM0;                                  \
    __builtin_amdgcn_s_setprio(1);          \
    mma_quad<0, 1>(acc, af, bf);            \
    __builtin_amdgcn_s_setprio(0);          \
    VMCNT4;                                 \
    BAR;                                    \
    /* P2 */                                \
    load_af(af, ldsA(PI, 1), ck);           \
    STAGE_B((PI) ^ 1, 1, KN);               \
    BAR;                                    \
    LGKM0;                                  \
    __builtin_amdgcn_s_setprio(1);          \
    mma_quad<1, 1>(acc, af, bf);            \
    __builtin_amdgcn_s_setprio(0);          \
    BAR;                                    \
    /* P3 */                                \
    load_bf(bf, ldsB(PI, 0), ck);           \
    STAGE_A((PI) ^ 1, 1, KN);               \
    BAR;                                    \
    LGKM0;                                  \
    __builtin_amdgcn_s_setprio(1);          \
    mma_quad<1, 0>(acc, af, bf);            \
    __builtin_amdgcn_s_setprio(0);          \
    VMCNT4;                                 \
    BAR;                                    \
  } while (0)

__global__ __launch_bounds__(512) void gemm8_kernel(
    const unsigned short* __restrict__ A, const unsigned short* __restrict__ Bw,
    const float* __restrict__ scale, float* __restrict__ C) {
  extern __shared__ __align__(16) char lds[];   // 131072 B

  const int tid = threadIdx.x;
  const int lane = tid & 63;
  const int lm = lane & 31;        // m (A) / n (B) / col (C)
  const int lh = lane >> 5;        // k-half selector
  const int wave = tid >> 6;
  const int wr = wave >> 2;        // 0..2 : wave row (128 rows each)
  const int wc = wave & 3;         // 0..4 : wave col (64 cols each)

  // XCD-aware block swizzle (512 blocks, 512 % 8 == 0 -> simple form).
  int wg = blockIdx.x;
  wg = ((wg & 7) << 6) | (wg >> 3);
  const int bx = wg & 15;          // n tile (16)
  const int by = wg >> 4;          // m tile (32)
  const size_t m_blk = (size_t)by * 256;
  const size_t n_blk = (size_t)bx * 256;

  const char* Ag = (const char*)(A + m_blk * K_DIM);
  const char* Bg = (const char*)(Bw + n_blk * K_DIM);

  // Staging geometry (per thread).
  const int u = tid >> 3;                       // 0..64 row-in-issue
  const int cs = (tid & 7) ^ (u & 7);           // swizzled global k-chunk
  const size_t gA0 = (size_t)u * 8192 + (size_t)cs * 16;
  const size_t gB0 = (size_t)((u & 31) + ((u >> 5) << 6)) * 8192 +
                     (size_t)cs * 16;

  // ds_read geometry.
  const int aBase = (lm + 64 * wr) * 128;
  const int bBase = (lm + 32 * wc) * 128;
  int ck[4];
#pragma unroll
  for (int t = 0; t < 4; ++t) ck[t] = (((2 * t + lh) ^ (lm & 7)) << 4);

  f32x16 acc[4][2] = {};
  bf16x8 af[2][4];
  bf16x8 bf[4];

  // Prologue: stage tile 0 (pi=0), drain its first two halves, rendezvous.
  STAGE_A(0, 0, 0);
  STAGE_B(0, 0, 0);
  STAGE_B(0, 1, 0);
  STAGE_A(0, 1, 0);
  VMCNT4;
  BAR;

  for (int it = 0; it < 32; ++it) {
    const int kb = it << 7;
    TILE(0, kb + 64);                 // compute tile 2it,   stage tile 2it+1
    TILE(1, (kb + 128) & 4095);       // compute tile 2it+1, stage tile 2it+2
  }

  // Epilogue with fused per-output-col (o) scale.
  const float sc0 = scale[n_blk + wc * 64 + lm];
  const float sc1 = scale[n_blk + wc * 64 + 32 + lm];
#pragma unroll
  for (int i = 0; i < 4; ++i) {
    const size_t mb = m_blk + wr * 128 + i * 32 + 4 * lh;
#pragma unroll
    for (int g = 0; g < 4; ++g) {
#pragma unroll
      for (int rr = 0; rr < 4; ++rr) {
        const size_t m = mb + 8 * g + rr;
        float* Crow = C + m * N_DIM + n_blk + wc * 64 + lm;
        Crow[0]  = acc[i][0][g * 4 + rr] * sc0;
        Crow[32] = acc[i][1][g * 4 + rr] * sc1;
      }
    }
  }
}

extern "C" void kernel_launch(void* const* d_in, const int* in_sizes, int n_in,
                              void* d_out, int out_size, void* d_ws, size_t ws_size,
                              hipStream_t stream) {
  const float* x     = (const float*)d_in[0];   // [4,2048,4096] fp32
  const int*   gidx  = (const int*)d_in[1];     // [4096,4096] int32
  const float* lut   = (const float*)d_in[2];   // [65536] fp32
  const float* scale = (const float*)d_in[3];   // [4096,1] fp32
  float* out = (float*)d_out;                   // [4,2048,4096] fp32

  // ws layout: W_bf16 [N,K] (33.5 MB) then A_bf16 [M,K] (67 MB).
  unsigned short* wbf = (unsigned short*)d_ws;
  unsigned short* abf = wbf + (size_t)N_DIM * K_DIM;

  dequant_w_kernel<<<dim3(512), dim3(1024), 0, stream>>>(gidx, lut, (int4*)wbf);
  cvt_x_kernel<<<dim3((M_DIM * (size_t)K_DIM) / 8 / 256), dim3(256), 0, stream>>>(
      (const float4*)x, (int4*)abf);
  gemm8_kernel<<<dim3(512), dim3(512), 131072, stream>>>(abf, wbf, scale, out);
}

// Round 2
// 499.577 us; speedup vs baseline: 1.1922x; 1.0473x over previous
//
#include <hip/hip_runtime.h>
#include <hip/hip_bf16.h>

// GhostLinear: out[m,o] = sum_k x[m,k] * lut[gidx[o,k]] * scale[o]
// M = B*S = 8192, N = OUT_F = 4096, K = IN_F = 4096.
// R5: (1) GEMM ported to the m201 geometry: 16x16x32 bf16 MFMA, 256x256/BK=64,
//     8 waves, st_16x32 swizzle (byte ^= ((byte>>9)&1)<<5) -- the HW-verified
//     ~zero-conflict pattern -- with interleaved half mapping and reg-held B
//     so per-tile LDS reads hit the 24-read/wave minimum (R4 was 28 + 4.0
//     conflict-cycles/read). vmcnt(4) counted protocol, setprio, XCD swizzle.
//     (2) dequant: single-pass full bf16 LUT in 128KB dynamic LDS, no
//     predication.

typedef __bf16 bf16x8 __attribute__((ext_vector_type(8)));
typedef float f32x4 __attribute__((ext_vector_type(4)));

#define AS1(p) ((__attribute__((address_space(1))) void*)(p))
#define AS3(p) ((__attribute__((address_space(3))) void*)(p))

static constexpr int M_DIM = 8192;   // B*S
static constexpr int N_DIM = 4096;   // OUT_F
static constexpr int K_DIM = 4096;   // IN_F

// ---------------------------------------------------------------------------
// Kernel 1: dequant W -> bf16. 512 blocks x 1024 thr. Whole LUT as bf16
// (65536 x 2B = 128 KB) lives in dynamic LDS -> ONE unpredicated gather pass.
// ---------------------------------------------------------------------------
__global__ __launch_bounds__(1024) void dequant_w_kernel(
    const int* __restrict__ idx, const float* __restrict__ lut,
    int4* __restrict__ wout) {
  extern __shared__ __align__(16) char smem[];
  unsigned short* lut_s = (unsigned short*)smem;   // 65536 entries
  const int tid = threadIdx.x;
  const int4* i4 = (const int4*)idx;
  const float4* lut4 = (const float4*)lut;

  // fill: 16384 float4s / 1024 thr = 16 iters.
#pragma unroll
  for (int i = 0; i < 16; ++i) {
    const int c = i * 1024 + tid;
    const float4 f = lut4[c];
    union { unsigned short u[4]; unsigned long long q; } s;
    __bf16 b0 = (__bf16)f.x, b1 = (__bf16)f.y, b2 = (__bf16)f.z, b3 = (__bf16)f.w;
    s.u[0] = *(const unsigned short*)&b0;
    s.u[1] = *(const unsigned short*)&b1;
    s.u[2] = *(const unsigned short*)&b2;
    s.u[3] = *(const unsigned short*)&b3;
    *(unsigned long long*)&lut_s[4 * c] = s.q;
  }
  __syncthreads();

#pragma unroll
  for (int it = 0; it < 4; ++it) {
    const int w = blockIdx.x * 4096 + it * 1024 + tid;
    const int4 a = i4[2 * w];
    const int4 b = i4[2 * w + 1];
    union { unsigned short u[8]; int4 q; } o;
    o.u[0] = lut_s[a.x]; o.u[1] = lut_s[a.y];
    o.u[2] = lut_s[a.z]; o.u[3] = lut_s[a.w];
    o.u[4] = lut_s[b.x]; o.u[5] = lut_s[b.y];
    o.u[6] = lut_s[b.z]; o.u[7] = lut_s[b.w];
    wout[w] = o.q;
  }
}

// ---------------------------------------------------------------------------
// Kernel 2: x fp32 -> bf16. One thread -> 8 elements.
// ---------------------------------------------------------------------------
__global__ __launch_bounds__(256) void cvt_x_kernel(
    const float4* __restrict__ x, int4* __restrict__ aout) {
  const int t = blockIdx.x * 256 + threadIdx.x;     // 4,194,304 threads
  const float4 a = x[2 * t];
  const float4 b = x[2 * t + 1];
  union { bf16x8 v; int4 q; } u;
  u.v[0] = (__bf16)a.x;  u.v[1] = (__bf16)a.y;
  u.v[2] = (__bf16)a.z;  u.v[3] = (__bf16)a.w;
  u.v[4] = (__bf16)b.x;  u.v[5] = (__bf16)b.y;
  u.v[6] = (__bf16)b.z;  u.v[7] = (__bf16)b.w;
  aout[t] = u.q;
}

// ---------------------------------------------------------------------------
// Kernel 3: C[M,N] = A[M,K](bf16) * W[N,K](bf16)^T, fp32 out, scale fused.
// m201 geometry: 256x256 tile, BK=64, 512 thr = 8 waves (2 wr x 4 wc), wave
// tile 128x64 via 16x16x32 bf16 MFMA (8 m-frags x 4 n-frags x 2 substeps).
//
// Half mapping (interleaved): A half h = global rows [128h, 128h+128);
// wave wr owns rows 64*wr..64*wr+63 of EACH half -> quadrant qm touches only
// A-half qm. B identical with 32-col slices (wave wc owns 32*wc.. of each
// half, quadrant qn -> B-half qn).
//
// LDS (128 KiB dynamic): A[pi][h][128 rows][128 B] @ pi*32768 + h*16384;
// B same @ +65536. st_16x32 swizzle: byte ^= ((byte>>9)&1)<<5, i.e. 16B-chunk
// c ^= 2*((row>>2)&1). Applied on the pre-swizzled GLOBAL source of
// global_load_lds (LDS dest linear, per rule #21) and on the ds_read addr.
// This is the HW-verified ~zero-conflict read pattern (m201: 0.086 extra
// cyc/read vs R4's measured 4.0).
//
// Phases per K-tile (quadrant order (0,0)(0,1)(1,1)(1,0); B frags of qn=0
// held in regs across the tile so Ph3 reads NOTHING -> 24 b128/wave/tile,
// the data minimum):
//   Ph0: read A-half0 (8) + B-half0 (4) | stage A0' | bar | lgkm0 | 16 MFMA
//        | vmcnt(4) | bar
//   Ph1: read B-half1 (4)              | stage B0' | ... | vmcnt(4) | bar
//   Ph2: read A-half1 (8)              | stage B1' | ... |    --    | bar
//   Ph3: (no reads)                    | stage A1' | ... | vmcnt(4) | bar
// Load accounting (2 loads/half): every vmcnt(4) drains exactly the half the
// next phase's ds_reads need; never 0 in the main loop.
// Fragment layouts (m89-verified family): A/B lane: row = lane&15,
// k = (lane>>4)*8 + e (+32*substep). C/D: col(n) = lane&15,
// row(m) = (lane>>4)*4 + reg.
// ---------------------------------------------------------------------------

__device__ __forceinline__ void ld_a(bf16x8 af[4][2], const char* p) {
#pragma unroll
  for (int i = 0; i < 4; ++i)
#pragma unroll
    for (int s = 0; s < 2; ++s)
      af[i][s] = *(const bf16x8*)(p + i * 2048 + s * 64);
}

__device__ __forceinline__ void ld_b(bf16x8 bf[2][2], const char* p) {
#pragma unroll
  for (int j = 0; j < 2; ++j)
#pragma unroll
    for (int s = 0; s < 2; ++s)
      bf[j][s] = *(const bf16x8*)(p + j * 2048 + s * 64);
}

__device__ __forceinline__ void quad(f32x4 acc[4][2], const bf16x8 af[4][2],
                                     const bf16x8 bf[2][2]) {
#pragma unroll
  for (int s = 0; s < 2; ++s)
#pragma unroll
    for (int i = 0; i < 4; ++i)
#pragma unroll
      for (int j = 0; j < 2; ++j)
        acc[i][j] = __builtin_amdgcn_mfma_f32_16x16x32_bf16(
            af[i][s], bf[j][s], acc[i][j], 0, 0, 0);
}

#define BAR __builtin_amdgcn_s_barrier()
#define VMCNT4 asm volatile("s_waitcnt vmcnt(4)" ::: "memory")
#define LGKM0                                          \
  do {                                                 \
    asm volatile("s_waitcnt lgkmcnt(0)" ::: "memory"); \
    __builtin_amdgcn_sched_barrier(0);                 \
  } while (0)

#define ldsA(PI, H) (lds + (PI) * 32768 + (H) * 16384 + aRd)
#define ldsB(PI, H) (lds + 65536 + (PI) * 32768 + (H) * 16384 + bRd)

// Stage one half-tile (128 rows x 128 B) = 2 x global_load_lds dwordx4.
// Global row = h*128 + (tid>>3) + 64*iss; source chunk pre-swizzled so the
// linear LDS dest matches the swizzled read.
#define STAGE_A(PI, H, KN)                                                     \
  do {                                                                         \
    const size_t so = sOfs + (size_t)(H) * 1048576 + (size_t)(KN) * 2;         \
    __builtin_amdgcn_global_load_lds(                                          \
        AS1(Ag + so), AS3(lds + (PI) * 32768 + (H) * 16384 + sDst), 16, 0, 0); \
    __builtin_amdgcn_global_load_lds(                                          \
        AS1(Ag + so + 524288),                                                 \
        AS3(lds + (PI) * 32768 + (H) * 16384 + 8192 + sDst), 16, 0, 0);        \
  } while (0)

#define STAGE_B(PI, H, KN)                                                     \
  do {                                                                         \
    const size_t so = sOfs + (size_t)(H) * 1048576 + (size_t)(KN) * 2;         \
    __builtin_amdgcn_global_load_lds(                                          \
        AS1(Bg + so), AS3(lds + 65536 + (PI) * 32768 + (H) * 16384 + sDst),    \
        16, 0, 0);                                                             \
    __builtin_amdgcn_global_load_lds(                                          \
        AS1(Bg + so + 524288),                                                 \
        AS3(lds + 65536 + (PI) * 32768 + (H) * 16384 + 8192 + sDst), 16, 0,    \
        0);                                                                    \
  } while (0)

#define TILE(PI, KN)                   \
  do {                                 \
    /* Ph0: quadrant (0,0) */          \
    ld_a(af, ldsA(PI, 0));             \
    ld_b(bf0, ldsB(PI, 0));            \
    STAGE_A((PI) ^ 1, 0, KN);          \
    BAR;                               \
    LGKM0;                             \
    __builtin_amdgcn_s_setprio(1);     \
    quad(acc[0][0], af, bf0);          \
    __builtin_amdgcn_s_setprio(0);     \
    VMCNT4;                            \
    BAR;                               \
    /* Ph1: quadrant (0,1) */          \
    ld_b(bf1, ldsB(PI, 1));            \
    STAGE_B((PI) ^ 1, 0, KN);          \
    BAR;                               \
    LGKM0;                             \
    __builtin_amdgcn_s_setprio(1);     \
    quad(acc[0][1], af, bf1);          \
    __builtin_amdgcn_s_setprio(0);     \
    VMCNT4;                            \
    BAR;                               \
    /* Ph2: quadrant (1,1) */          \
    ld_a(af, ldsA(PI, 1));             \
    STAGE_B((PI) ^ 1, 1, KN);          \
    BAR;                               \
    LGKM0;                             \
    __builtin_amdgcn_s_setprio(1);     \
    quad(acc[1][1], af, bf1);          \
    __builtin_amdgcn_s_setprio(0);     \
    BAR;                               \
    /* Ph3: quadrant (1,0), reg-only */\
    STAGE_A((PI) ^ 1, 1, KN);          \
    BAR;                               \
    __builtin_amdgcn_s_setprio(1);     \
    quad(acc[1][0], af, bf0);          \
    __builtin_amdgcn_s_setprio(0);     \
    VMCNT4;                            \
    BAR;                               \
  } while (0)

__global__ __launch_bounds__(512, 2) void gemm16_kernel(
    const unsigned short* __restrict__ A, const unsigned short* __restrict__ Bw,
    const float* __restrict__ scale, float* __restrict__ C) {
  extern __shared__ __align__(16) char smem[];
  char* lds = smem;   // 131072 B

  const int tid = threadIdx.x;
  const int lane = tid & 63;
  const int lt = lane & 15;                 // frag row (m / n / C-col)
  const int lq = lane >> 4;                 // k-quarter / C-row group
  const int swz = ((lane >> 2) & 1) << 5;   // st_16x32 read-side XOR
  const int wave = tid >> 6;
  const int wr = wave >> 2;                 // 0..1 : 64-row slice per half
  const int wc = wave & 3;                  // 0..3 : 32-col slice per half

  // XCD-aware block swizzle (512 blocks, 512 % 8 == 0 -> simple bijection).
  int wg = blockIdx.x;
  wg = ((wg & 7) << 6) | (wg >> 3);
  const int bx = wg & 15;           // n tile (16)
  const int by = wg >> 4;           // m tile (32)
  const size_t m_blk = (size_t)by * 256;
  const size_t n_blk = (size_t)bx * 256;

  const char* Ag = (const char*)(A + m_blk * K_DIM);
  const char* Bg = (const char*)(Bw + n_blk * K_DIM);

  // ds_read byte bases within a half-buffer (swizzled).
  const int aRd = (64 * wr + lt) * 128 + ((lq << 4) ^ swz);
  const int bRd = (32 * wc + lt) * 128 + ((lq << 4) ^ swz);

  // Staging: LDS dest linear (tid*16); global source chunk = inverse swizzle.
  const int c_log = (tid & 7) ^ ((tid >> 4) & 2);   // (tid&7) ^ 2*((r>>2)&1)
  const size_t sOfs = (size_t)(tid >> 3) * 8192 + (size_t)c_log * 16;
  const int sDst = tid * 16;

  f32x4 acc[2][2][4][2] = {};   // [qm][qn][i][j], 4 f32 each = 128 VGPR
  bf16x8 af[4][2];
  bf16x8 bf0[2][2];
  bf16x8 bf1[2][2];

  // Prologue: stage tile 0 in consumption order, drain first 2 halves.
  STAGE_A(0, 0, 0);
  STAGE_B(0, 0, 0);
  STAGE_B(0, 1, 0);
  STAGE_A(0, 1, 0);
  VMCNT4;
  BAR;

  for (int it = 0; it < 32; ++it) {
    const int kb = it << 7;
    TILE(0, kb + 64);               // compute tile 2it,   stage tile 2it+1
    TILE(1, (kb + 128) & 4095);     // compute tile 2it+1, stage tile 2it+2
  }

  // Epilogue: fused per-output-col (o = n) scale.
  float scv[2][2];
#pragma unroll
  for (int qn = 0; qn < 2; ++qn)
#pragma unroll
    for (int j = 0; j < 2; ++j)
      scv[qn][j] = scale[n_blk + qn * 128 + wc * 32 + j * 16 + lt];

#pragma unroll
  for (int qm = 0; qm < 2; ++qm)
#pragma unroll
    for (int i = 0; i < 4; ++i)
#pragma unroll
      for (int r = 0; r < 4; ++r) {
        const size_t m = m_blk + qm * 128 + wr * 64 + i * 16 + lq * 4 + r;
        float* Cm = C + m * N_DIM + n_blk + wc * 32 + lt;
#pragma unroll
        for (int qn = 0; qn < 2; ++qn)
#pragma unroll
          for (int j = 0; j < 2; ++j)
            Cm[qn * 128 + j * 16] = acc[qm][qn][i][j][r] * scv[qn][j];
      }
}

extern "C" void kernel_launch(void* const* d_in, const int* in_sizes, int n_in,
                              void* d_out, int out_size, void* d_ws, size_t ws_size,
                              hipStream_t stream) {
  const float* x     = (const float*)d_in[0];   // [4,2048,4096] fp32
  const int*   gidx  = (const int*)d_in[1];     // [4096,4096] int32
  const float* lut   = (const float*)d_in[2];   // [65536] fp32
  const float* scale = (const float*)d_in[3];   // [4096,1] fp32
  float* out = (float*)d_out;                   // [4,2048,4096] fp32

  // ws layout: W_bf16 [N,K] (33.5 MB) then A_bf16 [M,K] (67 MB).
  unsigned short* wbf = (unsigned short*)d_ws;
  unsigned short* abf = wbf + (size_t)N_DIM * K_DIM;

  dequant_w_kernel<<<dim3(512), dim3(1024), 131072, stream>>>(gidx, lut,
                                                              (int4*)wbf);
  cvt_x_kernel<<<dim3((M_DIM * (size_t)K_DIM) / 8 / 256), dim3(256), 0, stream>>>(
      (const float4*)x, (int4*)abf);
  gemm16_kernel<<<dim3(512), dim3(512), 131072, stream>>>(abf, wbf, scale, out);
}

// Round 3
// 478.341 us; speedup vs baseline: 1.2451x; 1.0444x over previous
//
#include <hip/hip_runtime.h>
#include <hip/hip_bf16.h>

// GhostLinear: out[m,o] = sum_k x[m,k] * lut[gidx[o,k]] * scale[o]
// M = B*S = 8192, N = OUT_F = 4096, K = IN_F = 4096.
// R6: (1) GEMM LDS swizzle fixed to the full 3-bit spread: chunk ^= (row&7)
//     (R5's 1-bit st_16x32 port left each ds_read_b128 on 4 of 8 bank-quads
//     = measured 4.0 extra cyc/read). Applied on BOTH the pre-swizzled
//     global_load_lds source and the ds_read address (rule #21). Schedule,
//     vmcnt protocol, setprio, XCD swizzle unchanged.
//     (2) cvt_x made fully coalesced (one float4 per lane; R5 had 32B lane
//     stride = half-density on both loads).

typedef __bf16 bf16x8 __attribute__((ext_vector_type(8)));
typedef float f32x4 __attribute__((ext_vector_type(4)));

#define AS1(p) ((__attribute__((address_space(1))) void*)(p))
#define AS3(p) ((__attribute__((address_space(3))) void*)(p))

static constexpr int M_DIM = 8192;   // B*S
static constexpr int N_DIM = 4096;   // OUT_F
static constexpr int K_DIM = 4096;   // IN_F

// ---------------------------------------------------------------------------
// Kernel 1: dequant W -> bf16. 512 blocks x 1024 thr. Whole LUT as bf16
// (65536 x 2B = 128 KB) in dynamic LDS -> ONE unpredicated gather pass.
// ---------------------------------------------------------------------------
__global__ __launch_bounds__(1024) void dequant_w_kernel(
    const int* __restrict__ idx, const float* __restrict__ lut,
    int4* __restrict__ wout) {
  extern __shared__ __align__(16) char smem[];
  unsigned short* lut_s = (unsigned short*)smem;   // 65536 entries
  const int tid = threadIdx.x;
  const int4* i4 = (const int4*)idx;
  const float4* lut4 = (const float4*)lut;

  // fill: 16384 float4s / 1024 thr = 16 iters.
#pragma unroll
  for (int i = 0; i < 16; ++i) {
    const int c = i * 1024 + tid;
    const float4 f = lut4[c];
    union { unsigned short u[4]; unsigned long long q; } s;
    __bf16 b0 = (__bf16)f.x, b1 = (__bf16)f.y, b2 = (__bf16)f.z, b3 = (__bf16)f.w;
    s.u[0] = *(const unsigned short*)&b0;
    s.u[1] = *(const unsigned short*)&b1;
    s.u[2] = *(const unsigned short*)&b2;
    s.u[3] = *(const unsigned short*)&b3;
    *(unsigned long long*)&lut_s[4 * c] = s.q;
  }
  __syncthreads();

#pragma unroll
  for (int it = 0; it < 4; ++it) {
    const int w = blockIdx.x * 4096 + it * 1024 + tid;
    const int4 a = i4[2 * w];
    const int4 b = i4[2 * w + 1];
    union { unsigned short u[8]; int4 q; } o;
    o.u[0] = lut_s[a.x]; o.u[1] = lut_s[a.y];
    o.u[2] = lut_s[a.z]; o.u[3] = lut_s[a.w];
    o.u[4] = lut_s[b.x]; o.u[5] = lut_s[b.y];
    o.u[6] = lut_s[b.z]; o.u[7] = lut_s[b.w];
    wout[w] = o.q;
  }
}

// ---------------------------------------------------------------------------
// Kernel 2: x fp32 -> bf16. One float4 per lane: 16B load / 8B store, both
// fully coalesced (R5 had 32B lane stride -> half-density transactions).
// ---------------------------------------------------------------------------
__global__ __launch_bounds__(256) void cvt_x_kernel(
    const float4* __restrict__ x, unsigned long long* __restrict__ aout) {
  const int t = blockIdx.x * 256 + threadIdx.x;     // 8,388,608 float4s
  const float4 a = x[t];
  union { unsigned short u[4]; unsigned long long q; } s;
  __bf16 b0 = (__bf16)a.x, b1 = (__bf16)a.y, b2 = (__bf16)a.z, b3 = (__bf16)a.w;
  s.u[0] = *(const unsigned short*)&b0;
  s.u[1] = *(const unsigned short*)&b1;
  s.u[2] = *(const unsigned short*)&b2;
  s.u[3] = *(const unsigned short*)&b3;
  aout[t] = s.q;
}

// ---------------------------------------------------------------------------
// Kernel 3: C[M,N] = A[M,K](bf16) * W[N,K](bf16)^T, fp32 out, scale fused.
// 256x256 tile, BK=64, 512 thr = 8 waves (2 wr x 4 wc), wave tile 128x64 via
// 16x16x32 bf16 MFMA.
//
// LDS (128 KiB dynamic): A[pi][h][128 rows][8 chunks of 16B] @ pi*32768 +
// h*16384; B same @ +65536. A half h = global rows [128h,128h+128); wave wr
// owns rows 64*wr.. of each half (quadrant qm -> A-half qm); B identical with
// 32-col slices.
//
// Swizzle (R6): LDS position p of row r holds global 16B-chunk  p ^ (r&7).
// Read: global chunk c=(s*4+lq) of row r sits at p = c ^ (r&7); since all
// frag rows of a lane share r&7 = lane&7, ck[s] = ((lq ^ (lane&7))<<4) ^
// (s<<6) is lane-constant. Wave spread per read: for each lq, lane&7 spans
// 0..7 -> all 8 bank-quads x 8 lanes = 8 words/bank = conflict-free minimum.
// Write: global_load_lds dest stays linear (tid*16); source chunk
// (tid&7) ^ ((tid>>3)&7) applies the same involution.
//
// Phases per K-tile (quadrants (0,0)(0,1)(1,1)(1,0); qn=0 B frags reg-held
// so Ph3 reads nothing; 24 b128/wave/tile = data minimum):
//   Ph0: rd A0(8)+B0(4) | stage A0' | bar | lgkm0 | 16 MFMA | vmcnt(4) | bar
//   Ph1: rd B1(4)       | stage B0' | bar | lgkm0 | 16 MFMA | vmcnt(4) | bar
//   Ph2: rd A1(8)       | stage B1' | bar | lgkm0 | 16 MFMA |    --    | bar
//   Ph3: (none)         | stage A1' | bar |       | 16 MFMA | vmcnt(4) | bar
// Load accounting (2 loads/STAGE): each vmcnt(4) drains exactly the half the
// next phase's ds_reads need; never 0 in the main loop.
// Fragment layouts (m89-verified): A/B lane: row = lane&15, k = (lane>>4)*8
// + e (+32*substep). C/D: col(n) = lane&15, row(m) = (lane>>4)*4 + reg.
// ---------------------------------------------------------------------------

__device__ __forceinline__ void ld_a(bf16x8 af[4][2], const char* p,
                                     const int ck[2]) {
#pragma unroll
  for (int i = 0; i < 4; ++i)
#pragma unroll
    for (int s = 0; s < 2; ++s)
      af[i][s] = *(const bf16x8*)(p + i * 2048 + ck[s]);
}

__device__ __forceinline__ void ld_b(bf16x8 bf[2][2], const char* p,
                                     const int ck[2]) {
#pragma unroll
  for (int j = 0; j < 2; ++j)
#pragma unroll
    for (int s = 0; s < 2; ++s)
      bf[j][s] = *(const bf16x8*)(p + j * 2048 + ck[s]);
}

__device__ __forceinline__ void quad(f32x4 acc[4][2], const bf16x8 af[4][2],
                                     const bf16x8 bf[2][2]) {
#pragma unroll
  for (int s = 0; s < 2; ++s)
#pragma unroll
    for (int i = 0; i < 4; ++i)
#pragma unroll
      for (int j = 0; j < 2; ++j)
        acc[i][j] = __builtin_amdgcn_mfma_f32_16x16x32_bf16(
            af[i][s], bf[j][s], acc[i][j], 0, 0, 0);
}

#define BAR __builtin_amdgcn_s_barrier()
#define VMCNT4 asm volatile("s_waitcnt vmcnt(4)" ::: "memory")
#define LGKM0                                          \
  do {                                                 \
    asm volatile("s_waitcnt lgkmcnt(0)" ::: "memory"); \
    __builtin_amdgcn_sched_barrier(0);                 \
  } while (0)

#define ldsA(PI, H) (lds + (PI) * 32768 + (H) * 16384 + aRd)
#define ldsB(PI, H) (lds + 65536 + (PI) * 32768 + (H) * 16384 + bRd)

// Stage one half-tile (128 rows x 128 B) = 2 x global_load_lds dwordx4.
#define STAGE_A(PI, H, KN)                                                     \
  do {                                                                         \
    const size_t so = sOfs + (size_t)(H) * 1048576 + (size_t)(KN) * 2;         \
    __builtin_amdgcn_global_load_lds(                                          \
        AS1(Ag + so), AS3(lds + (PI) * 32768 + (H) * 16384 + sDst), 16, 0, 0); \
    __builtin_amdgcn_global_load_lds(                                          \
        AS1(Ag + so + 524288),                                                 \
        AS3(lds + (PI) * 32768 + (H) * 16384 + 8192 + sDst), 16, 0, 0);        \
  } while (0)

#define STAGE_B(PI, H, KN)                                                     \
  do {                                                                         \
    const size_t so = sOfs + (size_t)(H) * 1048576 + (size_t)(KN) * 2;         \
    __builtin_amdgcn_global_load_lds(                                          \
        AS1(Bg + so), AS3(lds + 65536 + (PI) * 32768 + (H) * 16384 + sDst),    \
        16, 0, 0);                                                             \
    __builtin_amdgcn_global_load_lds(                                          \
        AS1(Bg + so + 524288),                                                 \
        AS3(lds + 65536 + (PI) * 32768 + (H) * 16384 + 8192 + sDst), 16, 0,    \
        0);                                                                    \
  } while (0)

#define TILE(PI, KN)                   \
  do {                                 \
    /* Ph0: quadrant (0,0) */          \
    ld_a(af, ldsA(PI, 0), ck);         \
    ld_b(bf0, ldsB(PI, 0), ck);        \
    STAGE_A((PI) ^ 1, 0, KN);          \
    BAR;                               \
    LGKM0;                             \
    __builtin_amdgcn_s_setprio(1);     \
    quad(acc[0][0], af, bf0);          \
    __builtin_amdgcn_s_setprio(0);     \
    VMCNT4;                            \
    BAR;                               \
    /* Ph1: quadrant (0,1) */          \
    ld_b(bf1, ldsB(PI, 1), ck);        \
    STAGE_B((PI) ^ 1, 0, KN);          \
    BAR;                               \
    LGKM0;                             \
    __builtin_amdgcn_s_setprio(1);     \
    quad(acc[0][1], af, bf1);          \
    __builtin_amdgcn_s_setprio(0);     \
    VMCNT4;                            \
    BAR;                               \
    /* Ph2: quadrant (1,1) */          \
    ld_a(af, ldsA(PI, 1), ck);         \
    STAGE_B((PI) ^ 1, 1, KN);          \
    BAR;                               \
    LGKM0;                             \
    __builtin_amdgcn_s_setprio(1);     \
    quad(acc[1][1], af, bf1);          \
    __builtin_amdgcn_s_setprio(0);     \
    BAR;                               \
    /* Ph3: quadrant (1,0), reg-only */\
    STAGE_A((PI) ^ 1, 1, KN);          \
    BAR;                               \
    __builtin_amdgcn_s_setprio(1);     \
    quad(acc[1][0], af, bf0);          \
    __builtin_amdgcn_s_setprio(0);     \
    VMCNT4;                            \
    BAR;                               \
  } while (0)

__global__ __launch_bounds__(512, 2) void gemm16_kernel(
    const unsigned short* __restrict__ A, const unsigned short* __restrict__ Bw,
    const float* __restrict__ scale, float* __restrict__ C) {
  extern __shared__ __align__(16) char smem[];
  char* lds = smem;   // 131072 B

  const int tid = threadIdx.x;
  const int lane = tid & 63;
  const int lt = lane & 15;                 // frag row (m / n / C-col)
  const int lq = lane >> 4;                 // k-quarter / C-row group
  const int wave = tid >> 6;
  const int wr = wave >> 2;                 // 0..1 : 64-row slice per half
  const int wc = wave & 3;                  // 0..3 : 32-col slice per half

  // XCD-aware block swizzle (512 blocks, 512 % 8 == 0 -> simple bijection).
  int wg = blockIdx.x;
  wg = ((wg & 7) << 6) | (wg >> 3);
  const int bx = wg & 15;           // n tile (16)
  const int by = wg >> 4;           // m tile (32)
  const size_t m_blk = (size_t)by * 256;
  const size_t n_blk = (size_t)bx * 256;

  const char* Ag = (const char*)(A + m_blk * K_DIM);
  const char* Bg = (const char*)(Bw + n_blk * K_DIM);

  // ds_read bases (row term only; chunk term in ck[]).
  const int aRd = (64 * wr + lt) * 128;
  const int bRd = (32 * wc + lt) * 128;
  const int xr = lane & 7;                  // row&7 for every frag this lane reads
  int ck[2];
  ck[0] = (lq ^ xr) << 4;
  ck[1] = ck[0] ^ 0x40;

  // Staging: LDS dest linear (tid*16); global source chunk = same involution.
  const int c_log = (tid & 7) ^ ((tid >> 3) & 7);
  const size_t sOfs = (size_t)(tid >> 3) * 8192 + (size_t)c_log * 16;
  const int sDst = tid * 16;

  f32x4 acc[2][2][4][2] = {};   // [qm][qn][i][j]
  bf16x8 af[4][2];
  bf16x8 bf0[2][2];
  bf16x8 bf1[2][2];

  // Prologue: stage tile 0 in consumption order, drain first 2 halves.
  STAGE_A(0, 0, 0);
  STAGE_B(0, 0, 0);
  STAGE_B(0, 1, 0);
  STAGE_A(0, 1, 0);
  VMCNT4;
  BAR;

  for (int it = 0; it < 32; ++it) {
    const int kb = it << 7;
    TILE(0, kb + 64);               // compute tile 2it,   stage tile 2it+1
    TILE(1, (kb + 128) & 4095);     // compute tile 2it+1, stage tile 2it+2
  }

  // Epilogue: fused per-output-col (o = n) scale.
  float scv[2][2];
#pragma unroll
  for (int qn = 0; qn < 2; ++qn)
#pragma unroll
    for (int j = 0; j < 2; ++j)
      scv[qn][j] = scale[n_blk + qn * 128 + wc * 32 + j * 16 + lt];

#pragma unroll
  for (int qm = 0; qm < 2; ++qm)
#pragma unroll
    for (int i = 0; i < 4; ++i)
#pragma unroll
      for (int r = 0; r < 4; ++r) {
        const size_t m = m_blk + qm * 128 + wr * 64 + i * 16 + lq * 4 + r;
        float* Cm = C + m * N_DIM + n_blk + wc * 32 + lt;
#pragma unroll
        for (int qn = 0; qn < 2; ++qn)
#pragma unroll
          for (int j = 0; j < 2; ++j)
            Cm[qn * 128 + j * 16] = acc[qm][qn][i][j][r] * scv[qn][j];
      }
}

extern "C" void kernel_launch(void* const* d_in, const int* in_sizes, int n_in,
                              void* d_out, int out_size, void* d_ws, size_t ws_size,
                              hipStream_t stream) {
  const float* x     = (const float*)d_in[0];   // [4,2048,4096] fp32
  const int*   gidx  = (const int*)d_in[1];     // [4096,4096] int32
  const float* lut   = (const float*)d_in[2];   // [65536] fp32
  const float* scale = (const float*)d_in[3];   // [4096,1] fp32
  float* out = (float*)d_out;                   // [4,2048,4096] fp32

  // ws layout: W_bf16 [N,K] (33.5 MB) then A_bf16 [M,K] (67 MB).
  unsigned short* wbf = (unsigned short*)d_ws;
  unsigned short* abf = wbf + (size_t)N_DIM * K_DIM;

  dequant_w_kernel<<<dim3(512), dim3(1024), 131072, stream>>>(gidx, lut,
                                                              (int4*)wbf);
  cvt_x_kernel<<<dim3((M_DIM * (size_t)K_DIM) / 4 / 256), dim3(256), 0, stream>>>(
      (const float4*)x, (unsigned long long*)abf);
  gemm16_kernel<<<dim3(512), dim3(512), 131072, stream>>>(abf, wbf, scale, out);
}